// Round 4
// baseline (300.424 us; speedup 1.0000x reference)
//
#include <hip/hip_runtime.h>
#include <hip/hip_bf16.h>

// MKGCN fused kernel. Inputs: float32 + int32; output: float32.
// R4: float4-ized gathers. Hop-2 hot loop uses (node, float4-lane, k-half)
// thread mapping: 8x 16B loads/thread, shuffle-xor(1) combine of k-halves.
// __launch_bounds__(256,8): cap VGPR at 64 to keep 8 blocks/CU (32 waves).

#define DIMV 32
#define KN   16
#define NREL 60
#define NT   256

__device__ __forceinline__ float sigmoidf_(float x) { return 1.0f / (1.0f + __expf(-x)); }

__global__ __launch_bounds__(NT, 8) void mkgcn_fused(
    const int* __restrict__ users,
    const int* __restrict__ items,
    const float* __restrict__ E,     // [1e6, 32]
    const float* __restrict__ R,     // [60, 32]
    const int* __restrict__ adjE,    // [1e6, 16]
    const int* __restrict__ adjR,    // [1e6, 16]
    const int* __restrict__ uhist,   // [1e5, 16]
    const float* __restrict__ Wg,    // [32, 32]
    const float* __restrict__ bg,    // [32]
    float* __restrict__ out)         // [B]
{
    const int b = blockIdx.x;
    const int t = threadIdx.x;

    __shared__ __align__(16) float Wl[DIMV][DIMV];   // 4 KB
    __shared__ __align__(16) float v1s[KN][DIMV];    // 2 KB hop-1 vectors
    __shared__ __align__(16) float x1s[KN][DIMV];    // 2 KB self+agg
    __shared__ __align__(16) float hv1[KN][DIMV];    // 2 KB updated hop-1
    __shared__ __align__(16) float part[8][DIMV];    // 1 KB history partials
    __shared__ int   e2[256];                        // hop-2 entity ids
    __shared__ int   r2[256];
    __shared__ float attn2[256];
    __shared__ float ue[DIMV];
    __shared__ float sdot[NREL];
    __shared__ float attn0[KN];
    __shared__ int   e1[KN];
    __shared__ int   r1[KN];
    __shared__ int   hrow[KN];
    __shared__ float bl[DIMV];
    __shared__ float v0c[DIMV];
    __shared__ float x0[DIMV];
    __shared__ float h0[DIMV];

    const int user = users[b];
    const int item = items[b];

    // ---- phase 0: index rows + W (float4) + v0/b ----
    if (t < KN) {
        hrow[t] = uhist[(long)user * KN + t];
    } else if (t < 2 * KN) {
        e1[t - KN] = adjE[(long)item * KN + (t - KN)];
    } else if (t < 3 * KN) {
        r1[t - 2 * KN] = adjR[(long)item * KN + (t - 2 * KN)];
    } else if (t >= 64 && t < 96) {
        v0c[t - 64] = E[(long)item * DIMV + (t - 64)];
        bl[t - 64]  = bg[t - 64];
    }
    ((float4*)Wl)[t] = ((const float4*)Wg)[t];   // 256 float4 = 1024 floats
    __syncthreads();

    // ---- phase 1: history (f4), hop-2 adjacency (int4), v1 (f4) ----
    if (t < 64) {
        const int r = t >> 3, v = t & 7;                 // r in 0..7
        const float4 a = ((const float4*)(E + (long)hrow[r] * DIMV))[v];
        const float4 c = ((const float4*)(E + (long)hrow[r + 8] * DIMV))[v];
        float4 s; s.x = a.x + c.x; s.y = a.y + c.y; s.z = a.z + c.z; s.w = a.w + c.w;
        ((float4*)part)[t] = s;
    } else if (t < 128) {
        const int i = t - 64;                            // n = i>>2, c = i&3
        const int n = i >> 2, c = i & 3;
        ((int4*)e2)[i] = ((const int4*)(adjE + (long)e1[n] * KN))[c];
    } else if (t < 192) {
        const int i = t - 128;
        const int n = i >> 2, c = i & 3;
        ((int4*)r2)[i] = ((const int4*)(adjR + (long)e1[n] * KN))[c];
    } else {
        const int i = t - 192;                           // 2 slots each: i, i+64
        {
            const int n = i >> 3, v = i & 7;
            ((float4*)v1s)[i] = ((const float4*)(E + (long)e1[n] * DIMV))[v];
        }
        {
            const int s = i + 64;
            const int n = s >> 3, v = s & 7;
            ((float4*)v1s)[s] = ((const float4*)(E + (long)e1[n] * DIMV))[v];
        }
    }
    __syncthreads();

    // ---- phase 2: user embedding ----
    if (t < DIMV) {
        float s = 0.f;
        #pragma unroll
        for (int r = 0; r < 8; r++) s += part[r][t];
        ue[t] = s * (1.0f / 16.0f);
    }
    __syncthreads();

    // ---- phase 3: sdot[r] = dot(ue, R[r]) ----
    if (t < NREL) {
        const float* rr = R + t * DIMV;
        float s = 0.f;
        #pragma unroll
        for (int d = 0; d < DIMV; d++) s += ue[d] * rr[d];
        sdot[t] = s;
    }
    __syncthreads();

    // ---- phase 4: softmax attention (16-lane segments) ----
    {
        float s = sdot[r2[t]];
        float m = s;
        #pragma unroll
        for (int off = 1; off < 16; off <<= 1) m = fmaxf(m, __shfl_xor(m, off, 16));
        float e = __expf(s - m);
        float sum = e;
        #pragma unroll
        for (int off = 1; off < 16; off <<= 1) sum += __shfl_xor(sum, off, 16);
        attn2[t] = e / sum;
    }
    if (t < KN) {
        float s = sdot[r1[t]];
        float m = s;
        #pragma unroll
        for (int off = 1; off < 16; off <<= 1) m = fmaxf(m, __shfl_xor(m, off, 16));
        float e = __expf(s - m);
        float sum = e;
        #pragma unroll
        for (int off = 1; off < 16; off <<= 1) sum += __shfl_xor(sum, off, 16);
        attn0[t] = e / sum;
    }
    __syncthreads();

    // ---- phase 5: hop-2 weighted gather (float4, k split in halves) ----
    {
        const int n  = t >> 4;          // 0..15
        const int v  = (t >> 1) & 7;    // float4 lane
        const int kh = t & 1;           // k half
        const int base = n * KN + kh * 8;
        float4 acc = make_float4(0.f, 0.f, 0.f, 0.f);
        #pragma unroll
        for (int k = 0; k < 8; k++) {
            const int row = e2[base + k];
            const float a = attn2[base + k];
            const float4 f = ((const float4*)(E + (long)row * DIMV))[v];
            acc.x += a * f.x; acc.y += a * f.y; acc.z += a * f.z; acc.w += a * f.w;
        }
        acc.x += __shfl_xor(acc.x, 1);
        acc.y += __shfl_xor(acc.y, 1);
        acc.z += __shfl_xor(acc.z, 1);
        acc.w += __shfl_xor(acc.w, 1);
        if (kh == 0) {
            const float4 vv = ((float4*)v1s)[n * 8 + v];
            float4 r; r.x = vv.x + acc.x; r.y = vv.y + acc.y;
            r.z = vv.z + acc.z; r.w = vv.w + acc.w;
            ((float4*)x1s)[n * 8 + v] = r;
        }
    }
    __syncthreads();

    // ---- phase 6: hop-1 matvec + sigmoid ----
    #pragma unroll
    for (int p = 0; p < 2; p++) {
        const int n = (t >> 5) + 8 * p;
        const int dp = t & 31;
        float acc = bl[dp];
        #pragma unroll
        for (int d = 0; d < DIMV; d++) acc += x1s[n][d] * Wl[d][dp];
        hv1[n][dp] = sigmoidf_(acc);
    }
    __syncthreads();

    // ---- phase 7: item aggregation over original hop-1 vectors ----
    if (t < DIMV) {
        float a = 0.f;
        #pragma unroll
        for (int k = 0; k < KN; k++) a += attn0[k] * v1s[k][t];
        x0[t] = v0c[t] + a;
    }
    __syncthreads();

    // ---- phase 8: item matvec + sigmoid ----
    if (t < DIMV) {
        float acc = bl[t];
        #pragma unroll
        for (int d = 0; d < DIMV; d++) acc += x0[d] * Wl[d][t];
        h0[t] = sigmoidf_(acc);
    }
    __syncthreads();

    // ---- phase 9: iteration-1 aggregation (same attn0) ----
    if (t < DIMV) {
        float a = 0.f;
        #pragma unroll
        for (int k = 0; k < KN; k++) a += attn0[k] * hv1[k][t];
        x0[t] = h0[t] + a;
    }
    __syncthreads();

    // ---- phase 10: final matvec + tanh, dot with ue, sigmoid ----
    if (t < DIMV) {
        float acc = bl[t];
        #pragma unroll
        for (int d = 0; d < DIMV; d++) acc += x0[d] * Wl[d][t];
        const float ie = tanhf(acc);
        float p = ue[t] * ie;
        #pragma unroll
        for (int off = 1; off < 32; off <<= 1) p += __shfl_xor(p, off, 32);
        if (t == 0) out[b] = sigmoidf_(p);
    }
}

extern "C" void kernel_launch(void* const* d_in, const int* in_sizes, int n_in,
                              void* d_out, int out_size, void* d_ws, size_t ws_size,
                              hipStream_t stream) {
    const int* users   = (const int*)d_in[0];
    const int* items   = (const int*)d_in[1];
    const float* E     = (const float*)d_in[2];
    const float* R     = (const float*)d_in[3];
    const int* adjE    = (const int*)d_in[4];
    const int* adjR    = (const int*)d_in[5];
    const int* uhist   = (const int*)d_in[6];
    const float* Wg    = (const float*)d_in[7];
    const float* bg    = (const float*)d_in[8];
    float* out         = (float*)d_out;

    const int B = in_sizes[0];
    mkgcn_fused<<<B, NT, 0, stream>>>(users, items, E, R, adjE, adjR, uhist, Wg, bg, out);
}

// Round 5
// 286.418 us; speedup vs baseline: 1.0489x; 1.0489x over previous
//
#include <hip/hip_runtime.h>
#include <hip/hip_bf16.h>

// MKGCN fused kernel. Inputs: float32 + int32; output: float32.
// R5: float4 gathers (R4) with UNCONSTRAINED register budget.
// R4 lesson: __launch_bounds__(256,8) drove VGPR to 32 -> spills (82 MB scratch
// writes) + serialized phase-5 loads. Plain __launch_bounds__(256) lets the
// 8 float4 loads/thread stay in flight.

#define DIMV 32
#define KN   16
#define NREL 60
#define NT   256

__device__ __forceinline__ float sigmoidf_(float x) { return 1.0f / (1.0f + __expf(-x)); }

__global__ __launch_bounds__(NT) void mkgcn_fused(
    const int* __restrict__ users,
    const int* __restrict__ items,
    const float* __restrict__ E,     // [1e6, 32]
    const float* __restrict__ R,     // [60, 32]
    const int* __restrict__ adjE,    // [1e6, 16]
    const int* __restrict__ adjR,    // [1e6, 16]
    const int* __restrict__ uhist,   // [1e5, 16]
    const float* __restrict__ Wg,    // [32, 32]
    const float* __restrict__ bg,    // [32]
    float* __restrict__ out)         // [B]
{
    const int b = blockIdx.x;
    const int t = threadIdx.x;

    __shared__ __align__(16) float Wl[DIMV][DIMV];   // 4 KB
    __shared__ __align__(16) float v1s[KN][DIMV];    // 2 KB hop-1 vectors
    __shared__ __align__(16) float x1s[KN][DIMV];    // 2 KB self+agg
    __shared__ __align__(16) float hv1[KN][DIMV];    // 2 KB updated hop-1
    __shared__ __align__(16) float part[8][DIMV];    // 1 KB history partials
    __shared__ int   e2[256];                        // hop-2 entity ids
    __shared__ int   r2[256];
    __shared__ float attn2[256];
    __shared__ float ue[DIMV];
    __shared__ float sdot[NREL];
    __shared__ float attn0[KN];
    __shared__ int   e1[KN];
    __shared__ int   r1[KN];
    __shared__ int   hrow[KN];
    __shared__ float bl[DIMV];
    __shared__ float v0c[DIMV];
    __shared__ float x0[DIMV];
    __shared__ float h0[DIMV];

    const int user = users[b];
    const int item = items[b];

    // ---- phase 0: index rows + W (float4) + v0/b ----
    if (t < KN) {
        hrow[t] = uhist[(long)user * KN + t];
    } else if (t < 2 * KN) {
        e1[t - KN] = adjE[(long)item * KN + (t - KN)];
    } else if (t < 3 * KN) {
        r1[t - 2 * KN] = adjR[(long)item * KN + (t - 2 * KN)];
    } else if (t >= 64 && t < 96) {
        v0c[t - 64] = E[(long)item * DIMV + (t - 64)];
        bl[t - 64]  = bg[t - 64];
    }
    ((float4*)Wl)[t] = ((const float4*)Wg)[t];   // 256 float4 = 1024 floats
    __syncthreads();

    // ---- phase 1: history (f4), hop-2 adjacency (int4), v1 (f4) ----
    if (t < 64) {
        const int r = t >> 3, v = t & 7;                 // r in 0..7
        const float4 a = ((const float4*)(E + (long)hrow[r] * DIMV))[v];
        const float4 c = ((const float4*)(E + (long)hrow[r + 8] * DIMV))[v];
        float4 s; s.x = a.x + c.x; s.y = a.y + c.y; s.z = a.z + c.z; s.w = a.w + c.w;
        ((float4*)part)[t] = s;
    } else if (t < 128) {
        const int i = t - 64;
        const int n = i >> 2, c = i & 3;
        ((int4*)e2)[i] = ((const int4*)(adjE + (long)e1[n] * KN))[c];
    } else if (t < 192) {
        const int i = t - 128;
        const int n = i >> 2, c = i & 3;
        ((int4*)r2)[i] = ((const int4*)(adjR + (long)e1[n] * KN))[c];
    } else {
        const int i = t - 192;                           // 2 slots each: i, i+64
        {
            const int n = i >> 3, v = i & 7;
            ((float4*)v1s)[i] = ((const float4*)(E + (long)e1[n] * DIMV))[v];
        }
        {
            const int s = i + 64;
            const int n = s >> 3, v = s & 7;
            ((float4*)v1s)[s] = ((const float4*)(E + (long)e1[n] * DIMV))[v];
        }
    }
    __syncthreads();

    // ---- phase 2: user embedding ----
    if (t < DIMV) {
        float s = 0.f;
        #pragma unroll
        for (int r = 0; r < 8; r++) s += part[r][t];
        ue[t] = s * (1.0f / 16.0f);
    }
    __syncthreads();

    // ---- phase 3: sdot[r] = dot(ue, R[r]) ----
    if (t < NREL) {
        const float* rr = R + t * DIMV;
        float s = 0.f;
        #pragma unroll
        for (int d = 0; d < DIMV; d++) s += ue[d] * rr[d];
        sdot[t] = s;
    }
    __syncthreads();

    // ---- phase 4: softmax attention (16-lane segments) ----
    {
        float s = sdot[r2[t]];
        float m = s;
        #pragma unroll
        for (int off = 1; off < 16; off <<= 1) m = fmaxf(m, __shfl_xor(m, off, 16));
        float e = __expf(s - m);
        float sum = e;
        #pragma unroll
        for (int off = 1; off < 16; off <<= 1) sum += __shfl_xor(sum, off, 16);
        attn2[t] = e / sum;
    }
    if (t < KN) {
        float s = sdot[r1[t]];
        float m = s;
        #pragma unroll
        for (int off = 1; off < 16; off <<= 1) m = fmaxf(m, __shfl_xor(m, off, 16));
        float e = __expf(s - m);
        float sum = e;
        #pragma unroll
        for (int off = 1; off < 16; off <<= 1) sum += __shfl_xor(sum, off, 16);
        attn0[t] = e / sum;
    }
    __syncthreads();

    // ---- phase 5: hop-2 weighted gather (float4, k split in halves) ----
    {
        const int n  = t >> 4;          // 0..15
        const int v  = (t >> 1) & 7;    // float4 lane
        const int kh = t & 1;           // k half
        const int base = n * KN + kh * 8;
        float4 acc = make_float4(0.f, 0.f, 0.f, 0.f);
        #pragma unroll
        for (int k = 0; k < 8; k++) {
            const int row = e2[base + k];
            const float a = attn2[base + k];
            const float4 f = ((const float4*)(E + (long)row * DIMV))[v];
            acc.x += a * f.x; acc.y += a * f.y; acc.z += a * f.z; acc.w += a * f.w;
        }
        acc.x += __shfl_xor(acc.x, 1);
        acc.y += __shfl_xor(acc.y, 1);
        acc.z += __shfl_xor(acc.z, 1);
        acc.w += __shfl_xor(acc.w, 1);
        if (kh == 0) {
            const float4 vv = ((float4*)v1s)[n * 8 + v];
            float4 r; r.x = vv.x + acc.x; r.y = vv.y + acc.y;
            r.z = vv.z + acc.z; r.w = vv.w + acc.w;
            ((float4*)x1s)[n * 8 + v] = r;
        }
    }
    __syncthreads();

    // ---- phase 6: hop-1 matvec + sigmoid ----
    #pragma unroll
    for (int p = 0; p < 2; p++) {
        const int n = (t >> 5) + 8 * p;
        const int dp = t & 31;
        float acc = bl[dp];
        #pragma unroll
        for (int d = 0; d < DIMV; d++) acc += x1s[n][d] * Wl[d][dp];
        hv1[n][dp] = sigmoidf_(acc);
    }
    __syncthreads();

    // ---- phase 7: item aggregation over original hop-1 vectors ----
    if (t < DIMV) {
        float a = 0.f;
        #pragma unroll
        for (int k = 0; k < KN; k++) a += attn0[k] * v1s[k][t];
        x0[t] = v0c[t] + a;
    }
    __syncthreads();

    // ---- phase 8: item matvec + sigmoid ----
    if (t < DIMV) {
        float acc = bl[t];
        #pragma unroll
        for (int d = 0; d < DIMV; d++) acc += x0[d] * Wl[d][t];
        h0[t] = sigmoidf_(acc);
    }
    __syncthreads();

    // ---- phase 9: iteration-1 aggregation (same attn0) ----
    if (t < DIMV) {
        float a = 0.f;
        #pragma unroll
        for (int k = 0; k < KN; k++) a += attn0[k] * hv1[k][t];
        x0[t] = h0[t] + a;
    }
    __syncthreads();

    // ---- phase 10: final matvec + tanh, dot with ue, sigmoid ----
    if (t < DIMV) {
        float acc = bl[t];
        #pragma unroll
        for (int d = 0; d < DIMV; d++) acc += x0[d] * Wl[d][t];
        const float ie = tanhf(acc);
        float p = ue[t] * ie;
        #pragma unroll
        for (int off = 1; off < 32; off <<= 1) p += __shfl_xor(p, off, 32);
        if (t == 0) out[b] = sigmoidf_(p);
    }
}

extern "C" void kernel_launch(void* const* d_in, const int* in_sizes, int n_in,
                              void* d_out, int out_size, void* d_ws, size_t ws_size,
                              hipStream_t stream) {
    const int* users   = (const int*)d_in[0];
    const int* items   = (const int*)d_in[1];
    const float* E     = (const float*)d_in[2];
    const float* R     = (const float*)d_in[3];
    const int* adjE    = (const int*)d_in[4];
    const int* adjR    = (const int*)d_in[5];
    const int* uhist   = (const int*)d_in[6];
    const float* Wg    = (const float*)d_in[7];
    const float* bg    = (const float*)d_in[8];
    float* out         = (float*)d_out;

    const int B = in_sizes[0];
    mkgcn_fused<<<B, NT, 0, stream>>>(users, items, E, R, adjE, adjR, uhist, Wg, bg, out);
}

// Round 6
// 284.083 us; speedup vs baseline: 1.0575x; 1.0082x over previous
//
#include <hip/hip_runtime.h>

// MKGCN — R6: wave-per-element. 4 independent batch elements per 256-thread
// block (one per wave). All phases full-wave on independent data; e2/attn in
// [k][n]-transposed LDS layout (conflict-free broadcast in hot loop); r2
// parked in x1 buffer; hv1 overwrites x1; history mean via register reduce.
// LDS ~31.4 KB/block -> 5 blocks/CU (20 waves). #pragma unroll 4 in hot loop
// keeps VGPR under ~100 (R4 lesson: don't starve; R5 lesson: don't bloat).

#define NT 256

__device__ __forceinline__ float sigmoidf_(float x) { return 1.0f / (1.0f + __expf(-x)); }

__global__ __launch_bounds__(NT) void mkgcn_wpe(
    const int* __restrict__ users,
    const int* __restrict__ items,
    const float* __restrict__ E,      // [1e6, 32]
    const float* __restrict__ R,      // [60, 32]
    const int* __restrict__ adjE,     // [1e6, 16]
    const int* __restrict__ adjR,     // [1e6, 16]
    const int* __restrict__ uhist,    // [1e5, 16]
    const float* __restrict__ Wg,     // [32, 32]
    const float* __restrict__ bg,     // [32]
    float* __restrict__ out,          // [B]
    int B)
{
    struct PE {
        int   e2[256];      // transposed: e2[k*16+n]
        float attn[256];    // transposed: attn[k*16+n]
        float v1[16][32];
        float x1[16][32];   // holds r2T (ints) early, x1 mid, hv1 late
        float ue[32];
        float sdot[64];
        float attn0[16];
        float v0[32];
        float x0[32];
        float h0[32];
    };
    __shared__ __align__(16) float Wl[32][32];
    __shared__ float bl[32];
    __shared__ __align__(16) PE pe[4];

    const int t = threadIdx.x;
    const int w = t >> 6;     // wave id
    const int L = t & 63;     // lane
    int b = blockIdx.x * 4 + w;
    if (b >= B) b = B - 1;    // tail clamp: duplicate compute, same value written
    PE& P = pe[w];

    const int user = users[b];
    const int item = items[b];

    // ---- P0: index rows (regs), v0, W/b ----
    int hid = 0, e1v = 0, r1v = 0;
    if (L < 16)       hid = uhist[(long)user * 16 + L];
    else if (L < 32)  e1v = adjE[(long)item * 16 + (L - 16)];
    else if (L < 48)  r1v = adjR[(long)item * 16 + (L - 32)];
    else if (L < 56)  ((float4*)P.v0)[L - 48] = ((const float4*)(E + (long)item * 32))[L - 48];
    ((float4*)Wl)[t] = ((const float4*)Wg)[t];
    if (t < 32) bl[t] = bg[t];

    const int v  = L & 7;     // float4 index within row
    const int r8 = L >> 3;    // row group 0..7

    // ---- P1: history mean (register reduce), hop-2 adjacency (transposed), v1 ----
    {
        const int h0i = __shfl(hid, r8);
        const int h1i = __shfl(hid, r8 + 8);
        const float4 a = ((const float4*)(E + (long)h0i * 32))[v];
        const float4 c = ((const float4*)(E + (long)h1i * 32))[v];
        float sx = a.x + c.x, sy = a.y + c.y, sz = a.z + c.z, sw = a.w + c.w;
        #pragma unroll
        for (int off = 8; off < 64; off <<= 1) {
            sx += __shfl_xor(sx, off); sy += __shfl_xor(sy, off);
            sz += __shfl_xor(sz, off); sw += __shfl_xor(sw, off);
        }
        if (L < 8) {   // lane L has v == L here
            float4 u; u.x = sx * 0.0625f; u.y = sy * 0.0625f;
            u.z = sz * 0.0625f; u.w = sw * 0.0625f;
            ((float4*)P.ue)[L] = u;
        }
    }
    {
        const int n = L >> 2, c4 = L & 3;
        const int e1n = __shfl(e1v, 16 + n);
        const int4 ev = ((const int4*)(adjE + (long)e1n * 16))[c4];
        const int4 rv = ((const int4*)(adjR + (long)e1n * 16))[c4];
        int* x1i = (int*)P.x1;
        P.e2[(c4 * 4 + 0) * 16 + n] = ev.x;  P.e2[(c4 * 4 + 1) * 16 + n] = ev.y;
        P.e2[(c4 * 4 + 2) * 16 + n] = ev.z;  P.e2[(c4 * 4 + 3) * 16 + n] = ev.w;
        x1i[(c4 * 4 + 0) * 16 + n] = rv.x;   x1i[(c4 * 4 + 1) * 16 + n] = rv.y;
        x1i[(c4 * 4 + 2) * 16 + n] = rv.z;   x1i[(c4 * 4 + 3) * 16 + n] = rv.w;
    }
    #pragma unroll
    for (int it = 0; it < 2; ++it) {
        const int r = r8 + 8 * it;
        const int e1r = __shfl(e1v, 16 + r);
        ((float4*)P.v1)[r * 8 + v] = ((const float4*)(E + (long)e1r * 32))[v];
    }
    __syncthreads();   // B1: ue, e2, r2T, v1, v0, W, bl

    // ---- P3: sdot[r] = dot(ue, R[r]) ----
    if (L < 60) {
        const float4* rr = (const float4*)(R + L * 32);
        const float4* uu = (const float4*)P.ue;
        float s = 0.f;
        #pragma unroll
        for (int j = 0; j < 8; ++j) {
            const float4 a = rr[j], u = uu[j];
            s += a.x * u.x + a.y * u.y + a.z * u.z + a.w * u.w;
        }
        P.sdot[L] = s;
    }
    __syncthreads();   // B2: sdot

    // ---- P4: softmax attention (segments of 16 lanes = fixed n, k varies) ----
    {
        const int* r2T = (const int*)P.x1;
        #pragma unroll
        for (int c = 0; c < 4; ++c) {
            const int k = L & 15, n = c * 4 + (L >> 4);
            const float s = P.sdot[r2T[k * 16 + n]];
            float m = s;
            #pragma unroll
            for (int off = 1; off < 16; off <<= 1) m = fmaxf(m, __shfl_xor(m, off, 16));
            const float e = __expf(s - m);
            float sum = e;
            #pragma unroll
            for (int off = 1; off < 16; off <<= 1) sum += __shfl_xor(sum, off, 16);
            P.attn[k * 16 + n] = e / sum;
        }
    }
    const int r1L = __shfl(r1v, 32 + (L & 15));   // hoisted: sources lanes 32..47
    if (L < 16) {
        const float s = P.sdot[r1L];
        float m = s;
        #pragma unroll
        for (int off = 1; off < 16; off <<= 1) m = fmaxf(m, __shfl_xor(m, off, 16));
        const float e = __expf(s - m);
        float sum = e;
        #pragma unroll
        for (int off = 1; off < 16; off <<= 1) sum += __shfl_xor(sum, off, 16);
        P.attn0[L] = e / sum;
    }
    __syncthreads();   // B3: attn, attn0; r2T dead

    // ---- P5: hop-2 weighted gather. lane = (node, quarter); 32 f4 loads/lane ----
    {
        const int n  = L >> 2;
        const int s0 = (L & 3) * 2;
        float ax0 = 0, ay0 = 0, az0 = 0, aw0 = 0;
        float ax1 = 0, ay1 = 0, az1 = 0, aw1 = 0;
        #pragma unroll 4
        for (int k = 0; k < 16; ++k) {
            const int   row = P.e2[k * 16 + n];     // conflict-free broadcast
            const float aw  = P.attn[k * 16 + n];
            const float4* er = (const float4*)(E + (long)row * 32);
            const float4 f0 = er[s0];
            const float4 f1 = er[s0 + 1];
            ax0 += aw * f0.x; ay0 += aw * f0.y; az0 += aw * f0.z; aw0 += aw * f0.w;
            ax1 += aw * f1.x; ay1 += aw * f1.y; az1 += aw * f1.z; aw1 += aw * f1.w;
        }
        const float4 va = ((const float4*)P.v1)[n * 8 + s0];
        const float4 vb = ((const float4*)P.v1)[n * 8 + s0 + 1];
        float4 xa, xb;
        xa.x = va.x + ax0; xa.y = va.y + ay0; xa.z = va.z + az0; xa.w = va.w + aw0;
        xb.x = vb.x + ax1; xb.y = vb.y + ay1; xb.z = vb.z + az1; xb.w = vb.w + aw1;
        ((float4*)P.x1)[n * 8 + s0]     = xa;
        ((float4*)P.x1)[n * 8 + s0 + 1] = xb;
    }
    __syncthreads();   // B4: x1

    // ---- P6: hop-1 matvec + sigmoid; hv1 overwrites x1 (all reads precede writes) ----
    const int dp = L & 31, half = L >> 5;
    {
        float hv[8];
        #pragma unroll
        for (int p = 0; p < 8; ++p) {
            const int n = p * 2 + half;
            float acc = bl[dp];
            #pragma unroll
            for (int d = 0; d < 32; ++d) acc += P.x1[n][d] * Wl[d][dp];
            hv[p] = sigmoidf_(acc);
        }
        #pragma unroll
        for (int p = 0; p < 8; ++p) P.x1[p * 2 + half][dp] = hv[p];
    }
    // ---- P7: item aggregation over original v1 ----
    if (L < 32) {
        float a = 0.f;
        #pragma unroll
        for (int k = 0; k < 16; ++k) a += P.attn0[k] * P.v1[k][L];
        P.x0[L] = P.v0[L] + a;
    }
    __syncthreads();   // B5: hv1(x1), x0

    // ---- P8: item matvec + sigmoid ----
    if (L < 32) {
        float acc = bl[L];
        #pragma unroll
        for (int d = 0; d < 32; ++d) acc += P.x0[d] * Wl[d][L];
        P.h0[L] = sigmoidf_(acc);
    }
    __syncthreads();   // B6: h0

    // ---- P9: iteration-1 aggregation (same attn0) over hv1 ----
    if (L < 32) {
        float a = 0.f;
        #pragma unroll
        for (int k = 0; k < 16; ++k) a += P.attn0[k] * P.x1[k][L];
        P.x0[L] = P.h0[L] + a;     // x0 reads (P8) done at B6
    }
    __syncthreads();   // B7: x0'

    // ---- P10: final matvec + tanh, dot(ue), sigmoid ----
    if (L < 32) {
        float acc = bl[L];
        #pragma unroll
        for (int d = 0; d < 32; ++d) acc += P.x0[d] * Wl[d][L];
        const float ie = tanhf(acc);
        float pr = P.ue[L] * ie;
        #pragma unroll
        for (int off = 1; off < 32; off <<= 1) pr += __shfl_xor(pr, off, 32);
        if (L == 0) out[b] = sigmoidf_(pr);
    }
}

extern "C" void kernel_launch(void* const* d_in, const int* in_sizes, int n_in,
                              void* d_out, int out_size, void* d_ws, size_t ws_size,
                              hipStream_t stream) {
    const int* users   = (const int*)d_in[0];
    const int* items   = (const int*)d_in[1];
    const float* E     = (const float*)d_in[2];
    const float* R     = (const float*)d_in[3];
    const int* adjE    = (const int*)d_in[4];
    const int* adjR    = (const int*)d_in[5];
    const int* uhist   = (const int*)d_in[6];
    const float* Wg    = (const float*)d_in[7];
    const float* bg    = (const float*)d_in[8];
    float* out         = (float*)d_out;

    const int B = in_sizes[0];
    const int grid = (B + 3) / 4;
    mkgcn_wpe<<<grid, NT, 0, stream>>>(users, items, E, R, adjE, adjR, uhist, Wg, bg, out, B);
}